// Round 1
// 7245.494 us; speedup vs baseline: 2.1597x; 2.1597x over previous
//
#include <hip/hip_runtime.h>
#include <math.h>

// Problem constants
#define NB_ 32          // GJ block size
#define NPH 16          // 512 / NB_
// B=32, L=512, H=768, T=8, DK=96, BT=256

// ---------------------------------------------------------------------------
// 1) Q/K projection: out[m][n] = x[m][:] . W[n][:] + bias[n]   (W row-major, "NT")
//    BM=128, BN=64, BK=16, 256 threads, 8x4 micro-tile. grid.z selects Wq/Wk.
// ---------------------------------------------------------------------------
__global__ __launch_bounds__(256) void proj_gemm(const float* __restrict__ x,
    const float* __restrict__ Wq, const float* __restrict__ bq,
    const float* __restrict__ Wk, const float* __restrict__ bk,
    float* __restrict__ Qb, float* __restrict__ Kb) {
  const float* W    = blockIdx.z ? Wk : Wq;
  const float* bias = blockIdx.z ? bk : bq;
  float* out        = blockIdx.z ? Kb : Qb;
  const int m0 = blockIdx.x * 128;
  const int n0 = blockIdx.y * 64;
  __shared__ float Xs[16][132];   // [k][m], stride 132 keeps f4 alignment + bank spread
  __shared__ float Ws[16][68];    // [k][n]
  const int tid = threadIdx.x;
  const int tm = tid & 15, tn = tid >> 4;   // both [0,16)
  float acc[8][4];
#pragma unroll
  for (int i = 0; i < 8; i++)
#pragma unroll
    for (int j = 0; j < 4; j++) acc[i][j] = 0.f;

  for (int kk = 0; kk < 768; kk += 16) {
    // load X tile 128x16 (512 float4)
#pragma unroll
    for (int rep = 0; rep < 2; rep++) {
      int fidx = tid + rep * 256;
      int row = fidx >> 2, f4i = fidx & 3;
      float4 v = ((const float4*)(x + (size_t)(m0 + row) * 768 + kk))[f4i];
      Xs[f4i * 4 + 0][row] = v.x; Xs[f4i * 4 + 1][row] = v.y;
      Xs[f4i * 4 + 2][row] = v.z; Xs[f4i * 4 + 3][row] = v.w;
    }
    { // load W tile 64x16 (256 float4)
      int row = tid >> 2, f4i = tid & 3;
      float4 v = ((const float4*)(W + (size_t)(n0 + row) * 768 + kk))[f4i];
      Ws[f4i * 4 + 0][row] = v.x; Ws[f4i * 4 + 1][row] = v.y;
      Ws[f4i * 4 + 2][row] = v.z; Ws[f4i * 4 + 3][row] = v.w;
    }
    __syncthreads();
#pragma unroll
    for (int k = 0; k < 16; k++) {
      float4 a0 = *(const float4*)&Xs[k][tm * 8];
      float4 a1 = *(const float4*)&Xs[k][tm * 8 + 4];
      float4 bv = *(const float4*)&Ws[k][tn * 4];
      float am[8] = {a0.x,a0.y,a0.z,a0.w,a1.x,a1.y,a1.z,a1.w};
      float bn[4] = {bv.x,bv.y,bv.z,bv.w};
#pragma unroll
      for (int i = 0; i < 8; i++)
#pragma unroll
        for (int j = 0; j < 4; j++) acc[i][j] += am[i] * bn[j];
    }
    __syncthreads();
  }
  float b0 = bias[n0 + tn * 4 + 0], b1 = bias[n0 + tn * 4 + 1];
  float b2 = bias[n0 + tn * 4 + 2], b3 = bias[n0 + tn * 4 + 3];
#pragma unroll
  for (int i = 0; i < 8; i++) {
    float4 o = {acc[i][0] + b0, acc[i][1] + b1, acc[i][2] + b2, acc[i][3] + b3};
    *(float4*)(out + (size_t)(m0 + tm * 8 + i) * 768 + n0 + tn * 4) = o;
  }
}

// ---------------------------------------------------------------------------
// 2) f[b,t,l] = x[b,l,:] . Wroot[t,:] + broot[t]
// ---------------------------------------------------------------------------
__global__ __launch_bounds__(256) void f_kernel(const float* __restrict__ x,
    const float* __restrict__ Wroot, const float* __restrict__ broot,
    float* __restrict__ fout) {
  int row = blockIdx.x * 256 + threadIdx.x;   // b*512+l
  int b = row >> 9, l = row & 511;
  float acc[8] = {0,0,0,0,0,0,0,0};
  const float4* xr = (const float4*)(x + (size_t)row * 768);
  for (int h4 = 0; h4 < 192; h4++) {
    float4 xv = xr[h4];
#pragma unroll
    for (int t = 0; t < 8; t++) {
      float4 wv = ((const float4*)(Wroot + (size_t)t * 768))[h4];
      acc[t] += xv.x * wv.x + xv.y * wv.y + xv.z * wv.z + xv.w * wv.w;
    }
  }
#pragma unroll
  for (int t = 0; t < 8; t++)
    fout[(size_t)((b * 8 + t) << 9) + l] = acc[t] + broot[t];
}

// ---------------------------------------------------------------------------
// 3) scores -> softmax -> A = exp(p)*(1-eye), written to d_out.
//    Register-lean rewrite: acc[16] + ONE kv float4 live in the inner loop
//    (old version held kv[8] (32 VGPRs) + acc[16] + unrolled qv -> hit the
//    256-VGPR cap and spilled ~5KB/thread of scratch = the 15 GB of HBM
//    traffic rocprof measured).
//    1-D grid, XCD-chunked: all 32 q-blocks of one (b,t) on one XCD so the
//    196KB K-slice stays L2-resident.
// ---------------------------------------------------------------------------
__global__ __launch_bounds__(256) void scores_kernel(const float* __restrict__ Qb,
    const float* __restrict__ Kb, const int* __restrict__ mask,
    float* __restrict__ A) {
  const int lin = blockIdx.x;                 // 8192 blocks
  const int xcd = lin & 7;
  const int idx = lin >> 3;                   // 0..1023 within XCD
  const int bt  = xcd * 32 + (idx >> 5);      // 32 bt per XCD, contiguous
  const int q0  = (idx & 31) * 16;
  const int b = bt >> 3, t = bt & 7;
  __shared__ float  S[16][512];
  __shared__ float4 Qs4[16][24];              // Q tile as float4 [q][d4]
  __shared__ float  part[16][16];
  __shared__ float  invsum[16];
  const int tid = threadIdx.x;
  for (int i = tid; i < 384; i += 256) {      // 16*24 float4
    int q = i / 24, f4 = i % 24;
    Qs4[q][f4] =
        ((const float4*)(Qb + (size_t)(b * 512 + q0 + q) * 768 + t * 96))[f4];
  }
  __syncthreads();
  const float scl = 0.10206207261596575f;     // 1/sqrt(96)
#pragma unroll 1
  for (int rep = 0; rep < 2; rep++) {
    const int k = rep * 256 + tid;
    const float4* kr = (const float4*)(Kb + (size_t)(b * 512 + k) * 768 + t * 96);
    float acc[16];
#pragma unroll
    for (int q = 0; q < 16; q++) acc[q] = 0.f;
#pragma unroll 4
    for (int f4 = 0; f4 < 24; f4++) {
      float4 kv = kr[f4];
#pragma unroll
      for (int q = 0; q < 16; q++) {
        float4 qv = Qs4[q][f4];               // wave-uniform -> LDS broadcast
        acc[q] += qv.x * kv.x + qv.y * kv.y + qv.z * kv.z + qv.w * kv.w;
      }
    }
    int mk = mask[b * 512 + k];
#pragma unroll
    for (int q = 0; q < 16; q++)
      S[q][k] = mk ? expf(acc[q] * scl) : 0.f;
  }
  __syncthreads();
  { // row sums; k = j + 16*i keeps lanes on 16 distinct banks (4-way max)
    int q = tid >> 4, j = tid & 15;
    float s = 0.f;
#pragma unroll
    for (int i = 0; i < 32; i++) s += S[q][j + 16 * i];
    part[q][j] = s;
  }
  __syncthreads();
  if (tid < 16) {
    float s = 0.f;
#pragma unroll
    for (int j = 0; j < 16; j++) s += part[tid][j];
    invsum[tid] = 1.f / fmaxf(s, 1e-30f);
  }
  __syncthreads();
#pragma unroll 1
  for (int rep = 0; rep < 2; rep++) {
    const int k = rep * 256 + tid;
#pragma unroll
    for (int q = 0; q < 16; q++) {
      float p = S[q][k] * invsum[q];
      float a = (q0 + q == k) ? 0.f : expf(p);
      A[(size_t)(bt * 512 + q0 + q) * 512 + k] = a;
    }
  }
}

// 4) deg[bt][k] = sum_q A[bt][q][k]
__global__ __launch_bounds__(256) void deg_kernel(const float* __restrict__ A,
                                                  float* __restrict__ deg) {
  int bt = blockIdx.y, k = blockIdx.x * 256 + threadIdx.x;
  const float* Ab = A + (size_t)bt * 262144;
  float s = 0.f;
  for (int q = 0; q < 512; q++) s += Ab[(size_t)q * 512 + k];
  deg[bt * 512 + k] = s;
}

// 5) M = Lbar:  row0 = f ; else -A + deg on diag
__global__ __launch_bounds__(128) void build_kernel(const float* __restrict__ A,
    const float* __restrict__ fin, const float* __restrict__ deg,
    float* __restrict__ M) {
  int q = blockIdx.x, bt = blockIdx.y, tid = threadIdx.x;
  size_t base = (size_t)bt * 262144;
  float4* Mo = (float4*)(M + base + (size_t)q * 512);
  if (q == 0) {
    Mo[tid] = ((const float4*)(fin + (size_t)bt * 512))[tid];
  } else {
    float4 a = ((const float4*)(A + base + (size_t)q * 512))[tid];
    float4 m = {-a.x, -a.y, -a.z, -a.w};
    int k0 = tid * 4;
    if (q >= k0 && q < k0 + 4) {
      float d = deg[bt * 512 + q];
      if      (q == k0    ) m.x += d;
      else if (q == k0 + 1) m.y += d;
      else if (q == k0 + 2) m.z += d;
      else                  m.w += d;
    }
    Mo[tid] = m;
  }
}

// ---------------------------------------------------------------------------
// 6a) Panel factorization: in-place GJ with partial pivoting over 32 pivot
//     columns. Panel (512x32) lives in VGPRs: 2 rows/thread. Records pivots.
// ---------------------------------------------------------------------------
__global__ __launch_bounds__(256) void panel_kernel(float* __restrict__ M,
                                                    int* __restrict__ pivr, int ph) {
  const int bt = blockIdx.x, tid = threadIdx.x;
  const int j0 = ph * NB_;
  __shared__ float rowj[NB_];
  __shared__ float bufj[NB_], bufr[NB_];
  __shared__ float pivval_s;
  __shared__ unsigned long long wred[4];
  __shared__ int pivlist[NB_];
  float* Mb = M + (size_t)bt * 262144;
  float r0[NB_], r1[NB_];
  {
    const float4* p0 = (const float4*)(Mb + (size_t)tid * 512 + j0);
    const float4* p1 = (const float4*)(Mb + (size_t)(tid + 256) * 512 + j0);
#pragma unroll
    for (int fi = 0; fi < 8; fi++) {
      float4 a = p0[fi];
      r0[4*fi] = a.x; r0[4*fi+1] = a.y; r0[4*fi+2] = a.z; r0[4*fi+3] = a.w;
      float4 c = p1[fi];
      r1[4*fi] = c.x; r1[4*fi+1] = c.y; r1[4*fi+2] = c.z; r1[4*fi+3] = c.w;
    }
  }
  const int lane = tid & 63, wv = tid >> 6;
  for (int l = 0; l < NB_; l++) {
    const int j = j0 + l;
    // extract column-l values of my rows (pre-swap)
    float v0 = 0.f, v1 = 0.f;
#pragma unroll
    for (int c = 0; c < NB_; c++) { v0 = (c == l) ? r0[c] : v0; v1 = (c == l) ? r1[c] : v1; }
    // pivot search over rows >= j
    float best = -1.f; int bidx = 0;
    if (tid >= j)        { best = fabsf(v0); bidx = tid; }
    if (tid + 256 >= j)  { float a1 = fabsf(v1); if (a1 > best) { best = a1; bidx = tid + 256; } }
    unsigned long long pk = (best >= 0.f)
        ? ((((unsigned long long)__float_as_uint(best)) << 32) | (unsigned)bidx) : 0ull;
#pragma unroll
    for (int off = 32; off > 0; off >>= 1) {
      unsigned long long o = __shfl_xor(pk, off, 64);
      if (o > pk) pk = o;
    }
    if (lane == 0) wred[wv] = pk;
    __syncthreads();
    unsigned long long ma = wred[0] > wred[1] ? wred[0] : wred[1];
    unsigned long long mb = wred[2] > wred[3] ? wred[2] : wred[3];
    if (mb > ma) ma = mb;
    const int r = (int)(unsigned)(ma & 0xffffffffull);
    // stage swap rows + pivot value
    if (tid == (r & 255)) {
      pivval_s = (r < 256) ? v0 : v1;
#pragma unroll
      for (int c = 0; c < NB_; c++) bufr[c] = (r < 256) ? r0[c] : r1[c];
    }
    if (tid == (j & 255)) {
#pragma unroll
      for (int c = 0; c < NB_; c++) bufj[c] = (j < 256) ? r0[c] : r1[c];
    }
    if (tid == 0) pivlist[l] = r;
    __syncthreads();
    const float p = pivval_s;
    const float rinv = 1.f / p;
    if (tid == (j & 255)) {     // new pivot row = (old row r)/p, col l -> 1/p
#pragma unroll
      for (int c = 0; c < NB_; c++) {
        float nv = (c == l) ? rinv : bufr[c] * rinv;
        if (j < 256) r0[c] = nv; else r1[c] = nv;
        rowj[c] = nv;
      }
    }
    if (r != j && tid == (r & 255)) {  // row r <- old row j
#pragma unroll
      for (int c = 0; c < NB_; c++) { if (r < 256) r0[c] = bufj[c]; else r1[c] = bufj[c]; }
    }
    __syncthreads();
    // eliminate all rows != j (full GJ update, in-place column rule)
    if (tid != j) {
      float m = 0.f;
#pragma unroll
      for (int c = 0; c < NB_; c++) m = (c == l) ? r0[c] : m;
#pragma unroll
      for (int c = 0; c < NB_; c++) r0[c] = ((c == l) ? 0.f : r0[c]) - m * rowj[c];
    }
    if (tid + 256 != j) {
      float m = 0.f;
#pragma unroll
      for (int c = 0; c < NB_; c++) m = (c == l) ? r1[c] : m;
#pragma unroll
      for (int c = 0; c < NB_; c++) r1[c] = ((c == l) ? 0.f : r1[c]) - m * rowj[c];
    }
    __syncthreads();
  }
  { // write back panel
    float4* p0 = (float4*)(Mb + (size_t)tid * 512 + j0);
    float4* p1 = (float4*)(Mb + (size_t)(tid + 256) * 512 + j0);
#pragma unroll
    for (int fi = 0; fi < 8; fi++) {
      float4 a = {r0[4*fi], r0[4*fi+1], r0[4*fi+2], r0[4*fi+3]};
      p0[fi] = a;
      float4 c = {r1[4*fi], r1[4*fi+1], r1[4*fi+2], r1[4*fi+3]};
      p1[fi] = c;
    }
  }
  if (tid < NB_) pivr[bt * 512 + j0 + tid] = pivlist[tid];
}

// ---------------------------------------------------------------------------
// 6b) Rest-of-matrix update: X <- X[perm] + (panel - I_block) * X[perm][blockrows]
//     One WG per (bt, 64-col tile). Panel columns skipped (already final).
// ---------------------------------------------------------------------------
__global__ __launch_bounds__(256) void update_kernel(float* __restrict__ M,
                                                     const int* __restrict__ pivr, int ph) {
  const int bt = blockIdx.y, t0 = blockIdx.x * 64;
  const int j0 = ph * NB_;
  __shared__ int perm_s[512];
  __shared__ short rowslot_s[512];
  __shared__ float Xb[NB_][64];
  __shared__ float staged[64][64];
  __shared__ int srcrow[64];
  __shared__ int cnt;
  const int tid = threadIdx.x;
  const int c = tid & 63, g = tid >> 6;
  float* Mb = M + (size_t)bt * 262144;
  for (int i = tid; i < 512; i += 256) { perm_s[i] = i; rowslot_s[i] = -1; }
  if (tid == 0) cnt = 0;
  __syncthreads();
  if (tid == 0) {
    for (int l = 0; l < NB_; l++) {
      int r = pivr[bt * 512 + j0 + l];
      int tp = perm_s[j0 + l]; perm_s[j0 + l] = perm_s[r]; perm_s[r] = tp;
    }
  }
  __syncthreads();
  for (int i = tid; i < 512; i += 256) {
    if (perm_s[i] != i) { int s = atomicAdd(&cnt, 1); rowslot_s[i] = (short)s; srcrow[s] = perm_s[i]; }
  }
  __syncthreads();
  const int nmv = cnt;   // <= 64
  for (int s = g; s < nmv; s += 4) staged[s][c] = Mb[(size_t)srcrow[s] * 512 + t0 + c];
  for (int l = g; l < NB_; l += 4) Xb[l][c] = Mb[(size_t)perm_s[j0 + l] * 512 + t0 + c];
  __syncthreads();
  float xb[NB_];
#pragma unroll
  for (int l = 0; l < NB_; l++) xb[l] = Xb[l][c];
  const int col = t0 + c;
  const bool colok = !(col >= j0 && col < j0 + NB_);
  for (int i = g * 128; i < g * 128 + 128; i++) {
    const float4* vp = (const float4*)(Mb + (size_t)i * 512 + j0);
    int rs = rowslot_s[i];
    float s = (rs >= 0) ? staged[rs][c] : Mb[(size_t)i * 512 + col];
#pragma unroll
    for (int fi = 0; fi < 8; fi++) {
      float4 v = vp[fi];
      s += v.x * xb[4*fi] + v.y * xb[4*fi+1] + v.z * xb[4*fi+2] + v.w * xb[4*fi+3];
    }
    if (i >= j0 && i < j0 + NB_) {     // subtract identity part of V
      int li = i - j0;
      float xs = 0.f;
#pragma unroll
      for (int l = 0; l < NB_; l++) xs = (l == li) ? xb[l] : xs;
      s -= xs;
    }
    if (colok) Mb[(size_t)i * 512 + col] = s;
  }
}

// 7) column unscramble map + diagonal of LLinv
__global__ __launch_bounds__(64) void colsrc_kernel(const float* __restrict__ M,
    const int* __restrict__ pivr, int* __restrict__ colsrc, float* __restrict__ diagv) {
  const int bt = blockIdx.x, tid = threadIdx.x;
  __shared__ int piv[512];
  __shared__ int cs[512];
  for (int i = tid; i < 512; i += 64) { piv[i] = pivr[bt * 512 + i]; cs[i] = i; }
  __syncthreads();
  if (tid == 0) {
    for (int j = 511; j >= 0; j--) { int r = piv[j]; int tp = cs[j]; cs[j] = cs[r]; cs[r] = tp; }
  }
  __syncthreads();
  const float* Mb = M + (size_t)bt * 262144;
  for (int i = tid; i < 512; i += 64) {
    colsrc[bt * 512 + i] = cs[i];
    diagv[bt * 512 + i] = Mb[(size_t)i * 512 + cs[i]];
  }
}

// ---------------------------------------------------------------------------
// 8) Final: att[k,q] = (k!=0)*A[q,k]*diag[k] - (q!=0)*A[q,k]*LLinv[k,q]
//    LLinv[k,q] = M[k][colsrc[q]]. In-place transpose-paired 64x64 tiles in d_out.
// ---------------------------------------------------------------------------
__global__ __launch_bounds__(256) void final_kernel(const float* __restrict__ M,
    const int* __restrict__ colsrc, const float* __restrict__ diagv,
    float* __restrict__ Aout) {
  const int bt = blockIdx.y;
  int x = blockIdx.x, ti = 0;
  while (x >= 8 - ti) { x -= 8 - ti; ti++; }
  const int tj = ti + x;
  const int tid = threadIdx.x, c = tid & 63, g = tid >> 6;
  __shared__ float Aa[64][65];
  __shared__ float Ab[64][65];
  __shared__ int csj[64], csi[64];
  __shared__ float dgi[64], dgj[64];
  const size_t base = (size_t)bt * 262144;
  const float* Mb = M + base;
  float* Ao = Aout + base;
  if (tid < 64)       { csj[tid] = colsrc[bt * 512 + tj * 64 + tid];
                        dgi[tid] = diagv[bt * 512 + ti * 64 + tid]; }
  else if (tid < 128) { int u = tid - 64;
                        csi[u] = colsrc[bt * 512 + ti * 64 + u];
                        dgj[u] = diagv[bt * 512 + tj * 64 + u]; }
  for (int rr = g; rr < 64; rr += 4)
    Aa[rr][c] = Ao[(size_t)(tj * 64 + rr) * 512 + ti * 64 + c];
  if (ti != tj)
    for (int rr = g; rr < 64; rr += 4)
      Ab[rr][c] = Ao[(size_t)(ti * 64 + rr) * 512 + tj * 64 + c];
  __syncthreads();
  for (int kk = g; kk < 64; kk += 4) {               // O1: rows Ti, cols Tj
    int krow = ti * 64 + kk, q = tj * 64 + c;
    float a = Aa[c][kk];
    float llv = Mb[(size_t)krow * 512 + csj[c]];
    float val = 0.f;
    if (krow != 0) val = a * dgi[kk];
    if (q != 0)    val -= a * llv;
    Ao[(size_t)krow * 512 + q] = val;
  }
  if (ti != tj) {
    for (int kk = g; kk < 64; kk += 4) {             // O2: rows Tj, cols Ti
      int krow = tj * 64 + kk, q = ti * 64 + c;
      float a = Ab[c][kk];
      float llv = Mb[(size_t)krow * 512 + csi[c]];
      float val = 0.f;
      if (krow != 0) val = a * dgj[kk];
      if (q != 0)    val -= a * llv;
      Ao[(size_t)krow * 512 + q] = val;
    }
  }
}

// ---------------------------------------------------------------------------
extern "C" void kernel_launch(void* const* d_in, const int* in_sizes, int n_in,
                              void* d_out, int out_size, void* d_ws, size_t ws_size,
                              hipStream_t stream) {
  const float* x     = (const float*)d_in[0];
  const int*   mask  = (const int*)d_in[1];
  const float* Wq    = (const float*)d_in[2];
  const float* bq    = (const float*)d_in[3];
  const float* Wk    = (const float*)d_in[4];
  const float* bk    = (const float*)d_in[5];
  const float* Wroot = (const float*)d_in[6];
  const float* broot = (const float*)d_in[7];
  float* A = (float*)d_out;                    // holds exp(p_attn) then final att

  float* ws = (float*)d_ws;
  size_t off = 0;
  float* M    = ws + off; off += (size_t)256 * 512 * 512;   // 256 MB
  float* Qb   = ws + off; off += (size_t)16384 * 768;       // 50 MB
  float* Kb   = ws + off; off += (size_t)16384 * 768;       // 50 MB
  float* fbuf = ws + off; off += (size_t)256 * 512;
  float* deg  = ws + off; off += (size_t)256 * 512;
  float* dgv  = ws + off; off += (size_t)256 * 512;
  int* pivr   = (int*)(ws + off); off += (size_t)256 * 512;
  int* csrc   = (int*)(ws + off); off += (size_t)256 * 512;
  if (ws_size < off * sizeof(float)) return;   // workspace too small: visible failure

  proj_gemm<<<dim3(128, 12, 2), 256, 0, stream>>>(x, Wq, bq, Wk, bk, Qb, Kb);
  f_kernel<<<64, 256, 0, stream>>>(x, Wroot, broot, fbuf);
  scores_kernel<<<dim3(8192), 256, 0, stream>>>(Qb, Kb, mask, A);
  deg_kernel<<<dim3(2, 256), 256, 0, stream>>>(A, deg);
  build_kernel<<<dim3(512, 256), 128, 0, stream>>>(A, fbuf, deg, M);
  for (int ph = 0; ph < NPH; ph++) {
    panel_kernel<<<256, 256, 0, stream>>>(M, pivr, ph);
    update_kernel<<<dim3(8, 256), 256, 0, stream>>>(M, pivr, ph);
  }
  colsrc_kernel<<<256, 64, 0, stream>>>(M, pivr, csrc, dgv);
  final_kernel<<<dim3(36, 256), 256, 0, stream>>>(M, csrc, dgv, A);
}